// Round 2
// baseline (877.428 us; speedup 1.0000x reference)
//
#include <hip/hip_runtime.h>
#include <hip/hip_bf16.h>

#define N_NODES 100000
#define N_USER  50000
#define D_IN    100
#define F_OUT   16
#define N_HEAD  3
#define N_TYPES 3
#define N_EDGES 1600000
#define D2      128
#define EPN     (N_EDGES + N_NODES)   // edges incl self-loops, per type

typedef __hip_bfloat16 bf16;
static __device__ __forceinline__ float b2f(bf16 x) { return __bfloat162float(x); }

// ---------------- workspace layout (float elements) ----------------
#define SZ_H   10000000
#define SZ_W   14400
#define SZ_B   144
#define SZ_AS  144
#define SZ_AT  144
#define SZ_W1  12800
#define SZ_W2  2048
#define SZ_M   128
#define CVT_TOTAL (SZ_H + SZ_W + SZ_B + SZ_AS + SZ_AT + SZ_W1 + SZ_W2 + SZ_M) // 10,029,808

#define OFF_CVT  64
#define OFF_CH   (OFF_CVT)
#define OFF_CW   (OFF_CH + SZ_H)
#define OFF_CB   (OFF_CW + SZ_W)
#define OFF_CAS  (OFF_CB + SZ_B)
#define OFF_CAT  (OFF_CAS + SZ_AS)
#define OFF_CW1  (OFF_CAT + SZ_AT)
#define OFF_CW2  (OFF_CW1 + SZ_W1)
#define OFF_CM   (OFF_CW2 + SZ_W2)
#define OFF_EI   (OFF_CVT + 10029824)          // int32, 9,600,000 slots
#define OFF_HP   (OFF_EI + 9600000)            // 14,400,000
#define OFF_P    (OFF_HP + 14400000)           // 900,032
#define OFF_NUM  (OFF_P + 900032)              // 7,200,000
#define OFF_DEN  (OFF_NUM + 7200000)           // 450,048
#define OFF_TA   (OFF_DEN + 450048)            // 2,400,000
#define OFF_FW1  (OFF_TA + 2400000)            // 6,400,000
// end = 51,379,968 floats ~= 196 MB

// ---------------------------------------------------------------------------
// Kernel 0: dtype detection. flags[0]=1 if float inputs are f32 (else bf16),
// flags[1]=1 if edge_index is int64 (else int32). Deterministic per launch.
// ---------------------------------------------------------------------------
__global__ void k_detect(const unsigned* __restrict__ hraw,
                         const unsigned* __restrict__ eiraw,
                         int* __restrict__ flags) {
    __shared__ int sane, nz;
    if (threadIdx.x == 0) { sane = 0; nz = 0; }
    __syncthreads();
    int cnt = 0; unsigned o = 0;
    for (int i = threadIdx.x; i < 1024; i += 256) {
        unsigned w = hraw[i];
        unsigned e = (w >> 23) & 0xFF;
        if (e >= 64 && e <= 200) cnt++;       // sane f32 exponent for N(0,1) data
        o |= eiraw[2 * i + 1];                // high words all-zero <=> int64
    }
    atomicAdd(&sane, cnt);
    atomicOr(&nz, (int)(o != 0));
    __syncthreads();
    if (threadIdx.x == 0) {
        flags[0] = (sane > 512) ? 1 : 0;   // 1 = float32 inputs
        flags[1] = nz ? 0 : 1;             // 1 = int64 edge_index
    }
}

// ---------------------------------------------------------------------------
// Kernel 0b: convert all float inputs -> f32 workspace copies (segment chain)
// ---------------------------------------------------------------------------
__global__ __launch_bounds__(256) void k_convert(
        const void* __restrict__ h, const void* __restrict__ W,
        const void* __restrict__ b, const void* __restrict__ as_,
        const void* __restrict__ at_, const void* __restrict__ w1,
        const void* __restrict__ w2, const void* __restrict__ m,
        const int* __restrict__ flags, float* __restrict__ cvt) {
    long long i = (long long)blockIdx.x * 256 + threadIdx.x;
    if (i >= (long long)CVT_TOTAL) return;
    const void* src; long long off;
    if      (i < SZ_H)                                { src = h;   off = i; }
    else if (i < SZ_H+SZ_W)                           { src = W;   off = i - SZ_H; }
    else if (i < SZ_H+SZ_W+SZ_B)                      { src = b;   off = i - (SZ_H+SZ_W); }
    else if (i < SZ_H+SZ_W+SZ_B+SZ_AS)                { src = as_; off = i - (SZ_H+SZ_W+SZ_B); }
    else if (i < SZ_H+SZ_W+SZ_B+SZ_AS+SZ_AT)          { src = at_; off = i - (SZ_H+SZ_W+SZ_B+SZ_AS); }
    else if (i < SZ_H+SZ_W+SZ_B+SZ_AS+SZ_AT+SZ_W1)    { src = w1;  off = i - (SZ_H+SZ_W+SZ_B+SZ_AS+SZ_AT); }
    else if (i < SZ_H+SZ_W+SZ_B+SZ_AS+SZ_AT+SZ_W1+SZ_W2) { src = w2; off = i - (SZ_H+SZ_W+SZ_B+SZ_AS+SZ_AT+SZ_W1); }
    else                                              { src = m;   off = i - (SZ_H+SZ_W+SZ_B+SZ_AS+SZ_AT+SZ_W1+SZ_W2); }
    float v = flags[0] ? ((const float*)src)[off] : b2f(((const bf16*)src)[off]);
    cvt[i] = v;
}

// Kernel 0c: convert edge_index -> int32 copy
__global__ __launch_bounds__(256) void k_convert_ei(const void* __restrict__ ei,
                                                    const int* __restrict__ flags,
                                                    int* __restrict__ cei) {
    long long i = (long long)blockIdx.x * 256 + threadIdx.x;
    if (i >= (long long)N_TYPES * 2 * N_EDGES) return;
    cei[i] = flags[1] ? (int)((const long long*)ei)[i] : ((const int*)ei)[i];
}

// ---------------------------------------------------------------------------
// Kernel 1: hp[t][n][48] = h[n,:] @ W[t] + b[t]
// ---------------------------------------------------------------------------
__global__ __launch_bounds__(256) void k_hp(const float* __restrict__ ch,
                                            const float* __restrict__ cW,
                                            const float* __restrict__ cb,
                                            float* __restrict__ hp) {
    __shared__ float hs[64][101];
    __shared__ float wsl[D_IN][48];
    const int tid = threadIdx.x;
    const int node0 = blockIdx.x * 64;
    for (int i = tid; i < 64 * D_IN; i += 256) {
        int r = i / D_IN, c = i % D_IN;
        int n = node0 + r;
        hs[r][c] = (n < N_NODES) ? ch[(size_t)n * D_IN + c] : 0.f;
    }
    const int u  = tid & 63;
    const int og = tid >> 6;   // 12 outputs each
    for (int t = 0; t < N_TYPES; ++t) {
        __syncthreads();
        for (int i = tid; i < D_IN * 48; i += 256)
            wsl[i / 48][i % 48] = cW[(size_t)t * D_IN * 48 + i];
        __syncthreads();
        float acc[12];
#pragma unroll
        for (int j = 0; j < 12; ++j) acc[j] = 0.f;
        for (int c = 0; c < D_IN; ++c) {
            float hv = hs[u][c];
            const float4* wr = (const float4*)&wsl[c][og * 12];
#pragma unroll
            for (int q = 0; q < 3; ++q) {
                float4 wv = wr[q];
                acc[q * 4 + 0] += hv * wv.x;
                acc[q * 4 + 1] += hv * wv.y;
                acc[q * 4 + 2] += hv * wv.z;
                acc[q * 4 + 3] += hv * wv.w;
            }
        }
        int n = node0 + u;
        if (n < N_NODES) {
#pragma unroll
            for (int j = 0; j < 12; ++j) {
                int jj = og * 12 + j;
                hp[(size_t)t * N_NODES * 48 + (size_t)n * 48 + jj] = acc[j] + cb[t * 48 + jj];
            }
        }
    }
}

// ---------------------------------------------------------------------------
// Kernel 2: p = exp(leaky_relu(hp . (a_src+a_trg)))  (max-shift is softmax-inv)
// ---------------------------------------------------------------------------
__global__ __launch_bounds__(256) void k_score(const float* __restrict__ hp,
                                               const float* __restrict__ cas,
                                               const float* __restrict__ cat,
                                               float* __restrict__ pbuf) {
    int idx = blockIdx.x * 256 + threadIdx.x;
    if (idx >= N_TYPES * N_NODES * N_HEAD) return;
    int k  = idx % 3;
    int tn = idx / 3;
    int n  = tn % N_NODES;
    int t  = tn / N_NODES;
    const float* row = hp + (size_t)t * N_NODES * 48 + (size_t)n * 48 + k * 16;
    float s = 0.f;
#pragma unroll
    for (int f = 0; f < 16; ++f)
        s += row[f] * (cas[(t * 3 + k) * 16 + f] + cat[(t * 3 + k) * 16 + f]);
    s = (s > 0.f) ? s : 0.2f * s;
    pbuf[idx] = expf(s);
}

// ---------------------------------------------------------------------------
// Kernel 3: edge scatter (16 lanes/edge; trg<N_USER only)
// ---------------------------------------------------------------------------
__global__ __launch_bounds__(256) void k_scatter(const int* __restrict__ cei,
                                                 const float* __restrict__ hp,
                                                 const float* __restrict__ pbuf,
                                                 float* __restrict__ numer,
                                                 float* __restrict__ denom) {
    long long gid = (long long)blockIdx.x * 256 + threadIdx.x;
    int eid = (int)(gid >> 4);
    int f   = (int)(gid & 15);
    if (eid >= N_TYPES * EPN) return;
    int t = eid / EPN;
    int i = eid - t * EPN;
    int src, trg;
    if (i < N_EDGES) {
        src = cei[(size_t)(t * 2) * N_EDGES + i];
        trg = cei[(size_t)(t * 2 + 1) * N_EDGES + i];
    } else {
        src = trg = i - N_EDGES;   // self-loop
    }
    if ((unsigned)trg >= N_USER) return;
    if ((unsigned)src >= N_NODES) return;
    const float* hrow = hp   + (size_t)t * N_NODES * 48 + (size_t)src * 48;
    const float* prow = pbuf + ((size_t)t * N_NODES + src) * 3;
    float* nrow = numer + ((size_t)t * N_USER + trg) * 48;
#pragma unroll
    for (int k = 0; k < 3; ++k) {
        float pk = prow[k];
        unsafeAtomicAdd(&nrow[k * 16 + f], pk * hrow[k * 16 + f]);
    }
    if (f < 3)
        unsafeAtomicAdd(&denom[((size_t)t * N_USER + trg) * 3 + f], prow[f]);
}

// ---------------------------------------------------------------------------
// Kernel 4: ta[v][t][f] = (1/3) * sum_k numer/(denom+1e-10)
// ---------------------------------------------------------------------------
__global__ __launch_bounds__(256) void k_final(const float* __restrict__ numer,
                                               const float* __restrict__ denom,
                                               float* __restrict__ ta) {
    int idx = blockIdx.x * 256 + threadIdx.x;
    if (idx >= N_USER * 48) return;
    int v = idx / 48;
    int r = idx % 48;
    int t = r / 16, f = r % 16;
    float s = 0.f;
#pragma unroll
    for (int k = 0; k < 3; ++k) {
        float d = denom[((size_t)t * N_USER + v) * 3 + k] + 1e-10f;
        s += numer[((size_t)t * N_USER + v) * 48 + k * 16 + f] / d;
    }
    ta[idx] = s * (1.f / 3.f);
}

// ---------------------------------------------------------------------------
// Kernel 5: fw1[v][j] = h[v,:] @ w1[:,j]
// ---------------------------------------------------------------------------
__global__ __launch_bounds__(256) void k_fw1(const float* __restrict__ ch,
                                             const float* __restrict__ cw1,
                                             float* __restrict__ fw1) {
    __shared__ float hs[64][101];
    __shared__ float wsl[D_IN][64];
    const int tid = threadIdx.x;
    const int v0 = blockIdx.x * 64;
    for (int i = tid; i < 64 * D_IN; i += 256) {
        int r = i / D_IN, c = i % D_IN;
        int v = v0 + r;
        hs[r][c] = (v < N_USER) ? ch[(size_t)v * D_IN + c] : 0.f;
    }
    const int u  = tid & 63;
    const int og = tid >> 6;
    for (int ph = 0; ph < 2; ++ph) {
        __syncthreads();
        for (int i = tid; i < D_IN * 64; i += 256)
            wsl[i / 64][i % 64] = cw1[(size_t)(i / 64) * D2 + ph * 64 + (i % 64)];
        __syncthreads();
        float acc[16];
#pragma unroll
        for (int j = 0; j < 16; ++j) acc[j] = 0.f;
        for (int c = 0; c < D_IN; ++c) {
            float hv = hs[u][c];
            const float4* wr = (const float4*)&wsl[c][og * 16];
#pragma unroll
            for (int q = 0; q < 4; ++q) {
                float4 wv = wr[q];
                acc[q * 4 + 0] += hv * wv.x;
                acc[q * 4 + 1] += hv * wv.y;
                acc[q * 4 + 2] += hv * wv.z;
                acc[q * 4 + 3] += hv * wv.w;
            }
        }
        int v = v0 + u;
        if (v < N_USER) {
#pragma unroll
            for (int j = 0; j < 16; ++j)
                fw1[(size_t)v * D2 + ph * 64 + og * 16 + j] = acc[j];
        }
    }
}

// ---------------------------------------------------------------------------
// Kernel 6: per-user fusion; output dtype keyed off flags[0]
// ---------------------------------------------------------------------------
__global__ __launch_bounds__(256) void k_fuse(const float* __restrict__ fw1,
                                              const float* __restrict__ ta,
                                              const float* __restrict__ cw2,
                                              const float* __restrict__ cm,
                                              const int* __restrict__ flags,
                                              void* __restrict__ out) {
    __shared__ float w2s[F_OUT][D2];
    __shared__ float ms[D2];
    __shared__ float tas[4][48];
    const int tid = threadIdx.x;
    for (int i = tid; i < F_OUT * D2; i += 256) w2s[i / D2][i % D2] = cw2[i];
    if (tid < D2) ms[tid] = cm[tid];
    const int w = tid >> 6, lane = tid & 63;
    const int v = blockIdx.x * 4 + w;
    if (lane < 48) tas[w][lane] = (v < N_USER) ? ta[(size_t)v * 48 + lane] : 0.f;
    __syncthreads();
    if (v >= N_USER) return;
    float f0 = fw1[(size_t)v * D2 + lane];
    float f1 = fw1[(size_t)v * D2 + 64 + lane];
    float sc[3];
#pragma unroll
    for (int t = 0; t < 3; ++t) {
        float z0 = f0, z1 = f1;
#pragma unroll
        for (int f = 0; f < 16; ++f) {
            float tv = tas[w][t * 16 + f];
            z0 += tv * w2s[f][lane];
            z1 += tv * w2s[f][64 + lane];
        }
        float q0 = 1.f - 2.f / (__expf(2.f * z0) + 1.f);   // tanh
        float q1 = 1.f - 2.f / (__expf(2.f * z1) + 1.f);
        float part = q0 * ms[lane] + q1 * ms[64 + lane];
#pragma unroll
        for (int off = 32; off > 0; off >>= 1)
            part += __shfl_xor(part, off, 64);
        sc[t] = part;
    }
    float mx = fmaxf(sc[0], fmaxf(sc[1], sc[2]));
    float e0 = __expf(sc[0] - mx), e1 = __expf(sc[1] - mx), e2 = __expf(sc[2] - mx);
    float inv = 1.f / (e0 + e1 + e2);
    float outv;
    if (lane < 16) {
        outv = (e0 * tas[w][lane] + e1 * tas[w][16 + lane] + e2 * tas[w][32 + lane]) * inv;
    } else {
        outv = tas[w][lane - 16];
    }
    size_t oidx = (size_t)v * 64 + lane;
    if (flags[0]) ((float*)out)[oidx] = outv;
    else          ((bf16*)out)[oidx]  = __float2bfloat16(outv);
}

// ---------------------------------------------------------------------------
extern "C" void kernel_launch(void* const* d_in, const int* in_sizes, int n_in,
                              void* d_out, int out_size, void* d_ws, size_t ws_size,
                              hipStream_t stream) {
    float* ws = (float*)d_ws;
    int*   flags = (int*)ws;              // ws[0..1]
    float* cvt  = ws + OFF_CVT;
    float* ch   = ws + OFF_CH;
    float* cW   = ws + OFF_CW;
    float* cb   = ws + OFF_CB;
    float* cas  = ws + OFF_CAS;
    float* cat  = ws + OFF_CAT;
    float* cw1  = ws + OFF_CW1;
    float* cw2  = ws + OFF_CW2;
    float* cm   = ws + OFF_CM;
    int*   cei  = (int*)(ws + OFF_EI);
    float* hp   = ws + OFF_HP;
    float* pbuf = ws + OFF_P;
    float* numer= ws + OFF_NUM;
    float* denom= ws + OFF_DEN;
    float* ta   = ws + OFF_TA;
    float* fw1  = ws + OFF_FW1;

    k_detect<<<1, 256, 0, stream>>>((const unsigned*)d_in[0], (const unsigned*)d_in[8], flags);
    {
        long long tot = CVT_TOTAL;
        k_convert<<<(int)((tot + 255) / 256), 256, 0, stream>>>(
            d_in[0], d_in[1], d_in[2], d_in[3], d_in[4], d_in[5], d_in[6], d_in[7],
            flags, cvt);
    }
    {
        long long tot = (long long)N_TYPES * 2 * N_EDGES;
        k_convert_ei<<<(int)((tot + 255) / 256), 256, 0, stream>>>(d_in[8], flags, cei);
    }

    hipMemsetAsync(numer, 0, (size_t)(7200000 + 450048) * sizeof(float), stream);

    k_hp<<<(N_NODES + 63) / 64, 256, 0, stream>>>(ch, cW, cb, hp);
    k_score<<<(N_TYPES * N_NODES * N_HEAD + 255) / 256, 256, 0, stream>>>(hp, cas, cat, pbuf);
    {
        long long total = (long long)N_TYPES * EPN * 16;
        k_scatter<<<(int)((total + 255) / 256), 256, 0, stream>>>(cei, hp, pbuf, numer, denom);
    }
    k_final<<<(N_USER * 48 + 255) / 256, 256, 0, stream>>>(numer, denom, ta);
    k_fw1<<<(N_USER + 63) / 64, 256, 0, stream>>>(ch, cw1, fw1);
    k_fuse<<<(N_USER + 3) / 4, 256, 0, stream>>>(fw1, ta, cw2, cm, flags, (void*)d_out);
}

// Round 3
// 697.584 us; speedup vs baseline: 1.2578x; 1.2578x over previous
//
#include <hip/hip_runtime.h>
#include <hip/hip_bf16.h>

#define N_NODES 100000
#define N_USER  50000
#define D_IN    100
#define F_OUT   16
#define N_HEAD  3
#define N_TYPES 3
#define N_EDGES 1600000
#define D2      128
#define N_SEG   (N_TYPES * N_USER)        // 150,000 (t, user) segments
#define N_SEG_PAD (147 * 1024)            // 150,528

typedef __hip_bfloat16 bf16;
static __device__ __forceinline__ float b2f(bf16 x) { return __bfloat162float(x); }

// ---------------- workspace layout (float elements) ----------------
// cvt weights: W 14400 | b 144 | as 144 | at 144 | w1 12800 | w2 2048 | m 128
#define OFF_CVT   64
#define OFF_CW    (OFF_CVT)
#define OFF_CB    (OFF_CW + 14400)
#define OFF_CAS   (OFF_CB + 144)
#define OFF_CAT   (OFF_CAS + 144)
#define OFF_CW1   (OFF_CAT + 144)
#define OFF_CW2   (OFF_CW1 + 12800)
#define OFF_CM    (OFF_CW2 + 2048)
#define CVT_TOTAL 29808
#define OFF_REC   29888                    // 300,000 records x 32 f32-words (128 B each)
#define OFF_CNT   (OFF_REC + 9600000)      // int[150528]
#define OFF_CUR   (OFF_CNT + N_SEG_PAD)    // int[150528]
#define OFF_BASE  (OFF_CUR + N_SEG_PAD)    // int[150528]
#define OFF_BSUM  (OFF_BASE + N_SEG_PAD)   // int[256]
#define OFF_BOFF  (OFF_BSUM + 256)         // int[256]
#define OFF_ELIST (OFF_BOFF + 256)         // int[4,800,000] (worst case)
#define OFF_TA    (OFF_ELIST + 4800000)    // f32[2,400,000]
#define OFF_FW1   (OFF_TA + 2400000)       // f32[6,400,000]
// end ~23.7M floats ~ 95 MB

// ---------------------------------------------------------------------------
// Kernel 0: dtype detection. flags[0]=1 if floats are f32 (else bf16),
// flags[1]=1 if edge_index is int64 (else int32).
// ---------------------------------------------------------------------------
__global__ void k_detect(const unsigned* __restrict__ hraw,
                         const unsigned* __restrict__ eiraw,
                         int* __restrict__ flags) {
    __shared__ int sane, nz;
    if (threadIdx.x == 0) { sane = 0; nz = 0; }
    __syncthreads();
    int cnt = 0; unsigned o = 0;
    for (int i = threadIdx.x; i < 1024; i += 256) {
        unsigned w = hraw[i];
        unsigned e = (w >> 23) & 0xFF;
        if (e >= 64 && e <= 200) cnt++;
        o |= eiraw[2 * i + 1];
    }
    atomicAdd(&sane, cnt);
    atomicOr(&nz, (int)(o != 0));
    __syncthreads();
    if (threadIdx.x == 0) {
        flags[0] = (sane > 512) ? 1 : 0;
        flags[1] = nz ? 0 : 1;
    }
}

// ---------------------------------------------------------------------------
// Kernel 0b: convert small weight tensors -> f32 workspace
// ---------------------------------------------------------------------------
__global__ __launch_bounds__(256) void k_convert_w(
        const void* __restrict__ W, const void* __restrict__ b,
        const void* __restrict__ as_, const void* __restrict__ at_,
        const void* __restrict__ w1, const void* __restrict__ w2,
        const void* __restrict__ m, const int* __restrict__ flags,
        float* __restrict__ cvt) {
    int i = blockIdx.x * 256 + threadIdx.x;
    if (i >= CVT_TOTAL) return;
    const void* src; int off;
    if      (i < 14400)                 { src = W;   off = i; }
    else if (i < 14400+144)             { src = b;   off = i - 14400; }
    else if (i < 14400+288)             { src = as_; off = i - 14544; }
    else if (i < 14400+432)             { src = at_; off = i - 14688; }
    else if (i < 14400+432+12800)       { src = w1;  off = i - 14832; }
    else if (i < 14400+432+12800+2048)  { src = w2;  off = i - 27632; }
    else                                { src = m;   off = i - 29680; }
    cvt[i] = flags[0] ? ((const float*)src)[off] : b2f(((const bf16*)src)[off]);
}

static __device__ __forceinline__ int load_ei(const void* ei, int f64, size_t pos) {
    return f64 ? (int)((const long long*)ei)[pos] : ((const int*)ei)[pos];
}

// ---------------------------------------------------------------------------
// Kernel 1: fused  h@W+b -> scores -> exp -> packed record
// rec[t*N_NODES+n] (128B): g[48] bf16 = p_k * hprime,  p[3] f32 at byte 96
// ---------------------------------------------------------------------------
__global__ __launch_bounds__(256) void k_hp_pack(const void* __restrict__ h,
                                                 const float* __restrict__ cW,
                                                 const float* __restrict__ cb,
                                                 const float* __restrict__ cas,
                                                 const float* __restrict__ cat,
                                                 const int* __restrict__ flags,
                                                 float* __restrict__ rec) {
    __shared__ float hs[64][101];
    __shared__ float wsl[4800];       // W tile [100][48], then out tile [64][48]
    __shared__ float psh[64][3];
    const int tid = threadIdx.x;
    const int node0 = blockIdx.x * 64;
    const int f32in = flags[0];
    for (int i = tid; i < 64 * D_IN; i += 256) {
        int r = i / D_IN, c = i % D_IN;
        int n = node0 + r;
        float v = 0.f;
        if (n < N_NODES)
            v = f32in ? ((const float*)h)[(size_t)n * D_IN + c]
                      : b2f(((const bf16*)h)[(size_t)n * D_IN + c]);
        hs[r][c] = v;
    }
    const int u  = tid & 63;
    const int og = tid >> 6;
    for (int t = 0; t < N_TYPES; ++t) {
        __syncthreads();
        for (int i = tid; i < D_IN * 48; i += 256)
            wsl[i] = cW[(size_t)t * D_IN * 48 + i];
        __syncthreads();
        float acc[12];
#pragma unroll
        for (int j = 0; j < 12; ++j) acc[j] = 0.f;
        for (int c = 0; c < D_IN; ++c) {
            float hv = hs[u][c];
            const float4* wr = (const float4*)&wsl[c * 48 + og * 12];
#pragma unroll
            for (int q = 0; q < 3; ++q) {
                float4 wv = wr[q];
                acc[q * 4 + 0] += hv * wv.x;
                acc[q * 4 + 1] += hv * wv.y;
                acc[q * 4 + 2] += hv * wv.z;
                acc[q * 4 + 3] += hv * wv.w;
            }
        }
        __syncthreads();   // done reading W tile; reuse wsl as out tile
#pragma unroll
        for (int j = 0; j < 12; ++j)
            wsl[u * 48 + og * 12 + j] = acc[j] + cb[t * 48 + og * 12 + j];
        __syncthreads();
        if (tid < 192) {
            int uu = tid & 63, k = tid >> 6;
            float s = 0.f;
#pragma unroll
            for (int f = 0; f < 16; ++f)
                s += wsl[uu * 48 + k * 16 + f] *
                     (cas[t * 48 + k * 16 + f] + cat[t * 48 + k * 16 + f]);
            s = (s > 0.f) ? s : 0.2f * s;
            psh[uu][k] = __expf(s);
        }
        __syncthreads();
        int n = node0 + u;
        if (n < N_NODES) {
            size_t nodei = (size_t)t * N_NODES + n;
            ushort* ru = (ushort*)rec + nodei * 64;
#pragma unroll
            for (int j = 0; j < 12; ++j) {
                int jj = og * 12 + j;
                float g = psh[u][jj >> 4] * wsl[u * 48 + jj];
                bf16 gb = __float2bfloat16(g);
                ru[jj] = *(ushort*)&gb;
            }
            if (og == 0) {
                float* rf = rec + nodei * 32;
                rf[24] = psh[u][0]; rf[25] = psh[u][1]; rf[26] = psh[u][2];
            }
        }
    }
}

// ---------------------------------------------------------------------------
// CSR build: histogram -> scan(3) -> fill
// ---------------------------------------------------------------------------
__global__ __launch_bounds__(256) void k_hist(const void* __restrict__ ei,
                                              const int* __restrict__ flags,
                                              int* __restrict__ counts) {
    int i = blockIdx.x * 256 + threadIdx.x;
    if (i >= N_TYPES * N_EDGES) return;
    int t = i / N_EDGES, e = i - t * N_EDGES;
    int trg = load_ei(ei, flags[1], (size_t)(t * 2 + 1) * N_EDGES + e);
    if ((unsigned)trg < N_USER) atomicAdd(&counts[t * N_USER + trg], 1);
}

__global__ __launch_bounds__(256) void k_scan1(const int* __restrict__ counts,
                                               int* __restrict__ bsum) {
    __shared__ int sd[256];
    int b = blockIdx.x, t = threadIdx.x;
    int i0 = b * 1024 + t * 4;
    int s = counts[i0] + counts[i0+1] + counts[i0+2] + counts[i0+3];
    sd[t] = s;
    for (int off = 128; off > 0; off >>= 1) {
        __syncthreads();
        if (t < off) sd[t] += sd[t + off];
    }
    if (t == 0) bsum[b] = sd[0];
}

__global__ void k_scan2(const int* __restrict__ bsum, int* __restrict__ boff) {
    __shared__ int sd[256];
    int t = threadIdx.x;
    int v = (t < 147) ? bsum[t] : 0;
    sd[t] = v;
    for (int off = 1; off < 256; off <<= 1) {
        __syncthreads();
        int x = (t >= off) ? sd[t - off] : 0;
        __syncthreads();
        sd[t] += x;
    }
    __syncthreads();
    if (t < 147) boff[t] = sd[t] - v;   // exclusive
}

__global__ __launch_bounds__(256) void k_scan3(const int* __restrict__ counts,
                                               const int* __restrict__ boff,
                                               int* __restrict__ base) {
    __shared__ int sd[256];
    int b = blockIdx.x, t = threadIdx.x;
    int i0 = b * 1024 + t * 4;
    int c0 = counts[i0], c1 = counts[i0+1], c2 = counts[i0+2], c3 = counts[i0+3];
    int s = c0 + c1 + c2 + c3;
    sd[t] = s;
    for (int off = 1; off < 256; off <<= 1) {
        __syncthreads();
        int x = (t >= off) ? sd[t - off] : 0;
        __syncthreads();
        sd[t] += x;
    }
    __syncthreads();
    int excl = sd[t] - s + boff[b];
    base[i0]   = excl;
    base[i0+1] = excl + c0;
    base[i0+2] = excl + c0 + c1;
    base[i0+3] = excl + c0 + c1 + c2;
}

__global__ __launch_bounds__(256) void k_fill(const void* __restrict__ ei,
                                              const int* __restrict__ flags,
                                              const int* __restrict__ base,
                                              int* __restrict__ cursor,
                                              int* __restrict__ elist) {
    int i = blockIdx.x * 256 + threadIdx.x;
    if (i >= N_TYPES * N_EDGES) return;
    int t = i / N_EDGES, e = i - t * N_EDGES;
    int f64 = flags[1];
    int trg = load_ei(ei, f64, (size_t)(t * 2 + 1) * N_EDGES + e);
    if ((unsigned)trg >= N_USER) return;
    int src = load_ei(ei, f64, (size_t)(t * 2) * N_EDGES + e);
    int tv = t * N_USER + trg;
    int pos = atomicAdd(&cursor[tv], 1);
    elist[base[tv] + pos] = src;
}

// ---------------------------------------------------------------------------
// Kernel 3: gather. One wave per (t, v). Two edges/iter via half-waves.
// virtual edge 0 = self loop. Writes ta[v][t][16] directly.
// ---------------------------------------------------------------------------
__global__ __launch_bounds__(256) void k_gather(const float* __restrict__ rec,
                                                const int* __restrict__ elist,
                                                const int* __restrict__ base,
                                                const int* __restrict__ counts,
                                                float* __restrict__ ta) {
    int wid = (blockIdx.x * 256 + threadIdx.x) >> 6;
    if (wid >= N_SEG) return;
    int lane = threadIdx.x & 63;
    int t = wid / N_USER, v = wid - t * N_USER;
    int cnt = counts[wid] + 1;          // + self loop
    int b0 = base[wid];
    int h = lane >> 5, l = lane & 31;
    const unsigned* recu = (const unsigned*)rec;
    float a0 = 0.f, a1 = 0.f, pacc = 0.f;
    for (int e = h; e < cnt; e += 2) {
        int src = (e == 0) ? v : elist[b0 + e - 1];
        size_t rb = ((size_t)t * N_NODES + src) * 32;
        if (l < 24) {
            unsigned w = recu[rb + l];
            a0 += __uint_as_float(w << 16);
            a1 += __uint_as_float(w & 0xffff0000u);
        } else if (l < 27) {
            pacc += rec[rb + 24 + (l - 24)];
        }
    }
    a0 += __shfl_xor(a0, 32);
    a1 += __shfl_xor(a1, 32);
    pacc += __shfl_xor(pacc, 32);
    int k = (l >> 3); if (k > 2) k = 2;
    float dk = __shfl(pacc, 24 + k) + 1e-10f;
    float r0 = a0 / dk, r1 = a1 / dk;
    float s0 = r0 + __shfl(r0, (l & 7) + 8) + __shfl(r0, (l & 7) + 16);
    float s1 = r1 + __shfl(r1, (l & 7) + 8) + __shfl(r1, (l & 7) + 16);
    if (lane < 8) {
        float2 o;
        o.x = s0 * (1.f / 3.f);
        o.y = s1 * (1.f / 3.f);
        *(float2*)&ta[(size_t)v * 48 + t * 16 + 2 * lane] = o;
    }
}

// ---------------------------------------------------------------------------
// Kernel 5: fw1[v][j] = h[v,:] @ w1[:,j]
// ---------------------------------------------------------------------------
__global__ __launch_bounds__(256) void k_fw1(const void* __restrict__ h,
                                             const float* __restrict__ cw1,
                                             const int* __restrict__ flags,
                                             float* __restrict__ fw1) {
    __shared__ float hs[64][101];
    __shared__ float wsl[D_IN][64];
    const int tid = threadIdx.x;
    const int v0 = blockIdx.x * 64;
    const int f32in = flags[0];
    for (int i = tid; i < 64 * D_IN; i += 256) {
        int r = i / D_IN, c = i % D_IN;
        int v = v0 + r;
        float x = 0.f;
        if (v < N_USER)
            x = f32in ? ((const float*)h)[(size_t)v * D_IN + c]
                      : b2f(((const bf16*)h)[(size_t)v * D_IN + c]);
        hs[r][c] = x;
    }
    const int u  = tid & 63;
    const int og = tid >> 6;
    for (int ph = 0; ph < 2; ++ph) {
        __syncthreads();
        for (int i = tid; i < D_IN * 64; i += 256)
            wsl[i / 64][i % 64] = cw1[(size_t)(i / 64) * D2 + ph * 64 + (i % 64)];
        __syncthreads();
        float acc[16];
#pragma unroll
        for (int j = 0; j < 16; ++j) acc[j] = 0.f;
        for (int c = 0; c < D_IN; ++c) {
            float hv = hs[u][c];
            const float4* wr = (const float4*)&wsl[c][og * 16];
#pragma unroll
            for (int q = 0; q < 4; ++q) {
                float4 wv = wr[q];
                acc[q * 4 + 0] += hv * wv.x;
                acc[q * 4 + 1] += hv * wv.y;
                acc[q * 4 + 2] += hv * wv.z;
                acc[q * 4 + 3] += hv * wv.w;
            }
        }
        int v = v0 + u;
        if (v < N_USER) {
#pragma unroll
            for (int j = 0; j < 16; ++j)
                fw1[(size_t)v * D2 + ph * 64 + og * 16 + j] = acc[j];
        }
    }
}

// ---------------------------------------------------------------------------
// Kernel 6: per-user fusion; output dtype keyed off flags[0]
// ---------------------------------------------------------------------------
__global__ __launch_bounds__(256) void k_fuse(const float* __restrict__ fw1,
                                              const float* __restrict__ ta,
                                              const float* __restrict__ cw2,
                                              const float* __restrict__ cm,
                                              const int* __restrict__ flags,
                                              void* __restrict__ out) {
    __shared__ float w2s[F_OUT][D2];
    __shared__ float ms[D2];
    __shared__ float tas[4][48];
    const int tid = threadIdx.x;
    for (int i = tid; i < F_OUT * D2; i += 256) w2s[i / D2][i % D2] = cw2[i];
    if (tid < D2) ms[tid] = cm[tid];
    const int w = tid >> 6, lane = tid & 63;
    const int v = blockIdx.x * 4 + w;
    if (lane < 48) tas[w][lane] = (v < N_USER) ? ta[(size_t)v * 48 + lane] : 0.f;
    __syncthreads();
    if (v >= N_USER) return;
    float f0 = fw1[(size_t)v * D2 + lane];
    float f1 = fw1[(size_t)v * D2 + 64 + lane];
    float sc[3];
#pragma unroll
    for (int t = 0; t < 3; ++t) {
        float z0 = f0, z1 = f1;
#pragma unroll
        for (int f = 0; f < 16; ++f) {
            float tv = tas[w][t * 16 + f];
            z0 += tv * w2s[f][lane];
            z1 += tv * w2s[f][64 + lane];
        }
        float q0 = 1.f - 2.f / (__expf(2.f * z0) + 1.f);
        float q1 = 1.f - 2.f / (__expf(2.f * z1) + 1.f);
        float part = q0 * ms[lane] + q1 * ms[64 + lane];
#pragma unroll
        for (int off = 32; off > 0; off >>= 1)
            part += __shfl_xor(part, off, 64);
        sc[t] = part;
    }
    float mx = fmaxf(sc[0], fmaxf(sc[1], sc[2]));
    float e0 = __expf(sc[0] - mx), e1 = __expf(sc[1] - mx), e2 = __expf(sc[2] - mx);
    float inv = 1.f / (e0 + e1 + e2);
    float outv;
    if (lane < 16) {
        outv = (e0 * tas[w][lane] + e1 * tas[w][16 + lane] + e2 * tas[w][32 + lane]) * inv;
    } else {
        outv = tas[w][lane - 16];
    }
    size_t oidx = (size_t)v * 64 + lane;
    if (flags[0]) ((float*)out)[oidx] = outv;
    else          ((bf16*)out)[oidx]  = __float2bfloat16(outv);
}

// ---------------------------------------------------------------------------
extern "C" void kernel_launch(void* const* d_in, const int* in_sizes, int n_in,
                              void* d_out, int out_size, void* d_ws, size_t ws_size,
                              hipStream_t stream) {
    float* ws = (float*)d_ws;
    int*   flags = (int*)ws;
    float* cvt   = ws + OFF_CVT;
    float* cW    = ws + OFF_CW;
    float* cb    = ws + OFF_CB;
    float* cas   = ws + OFF_CAS;
    float* cat   = ws + OFF_CAT;
    float* cw1   = ws + OFF_CW1;
    float* cw2   = ws + OFF_CW2;
    float* cm    = ws + OFF_CM;
    float* rec   = ws + OFF_REC;
    int*   counts= (int*)(ws + OFF_CNT);
    int*   cursor= (int*)(ws + OFF_CUR);
    int*   base  = (int*)(ws + OFF_BASE);
    int*   bsum  = (int*)(ws + OFF_BSUM);
    int*   boff  = (int*)(ws + OFF_BOFF);
    int*   elist = (int*)(ws + OFF_ELIST);
    float* ta    = ws + OFF_TA;
    float* fw1   = ws + OFF_FW1;

    k_detect<<<1, 256, 0, stream>>>((const unsigned*)d_in[0], (const unsigned*)d_in[8], flags);
    k_convert_w<<<(CVT_TOTAL + 255) / 256, 256, 0, stream>>>(
        d_in[1], d_in[2], d_in[3], d_in[4], d_in[5], d_in[6], d_in[7], flags, cvt);
    hipMemsetAsync(counts, 0, (size_t)2 * N_SEG_PAD * sizeof(int), stream);

    k_hp_pack<<<(N_NODES + 63) / 64, 256, 0, stream>>>(d_in[0], cW, cb, cas, cat, flags, rec);

    int eb = (N_TYPES * N_EDGES + 255) / 256;
    k_hist<<<eb, 256, 0, stream>>>(d_in[8], flags, counts);
    k_scan1<<<147, 256, 0, stream>>>(counts, bsum);
    k_scan2<<<1, 256, 0, stream>>>(bsum, boff);
    k_scan3<<<147, 256, 0, stream>>>(counts, boff, base);
    k_fill<<<eb, 256, 0, stream>>>(d_in[8], flags, base, cursor, elist);

    k_gather<<<(N_SEG * 64 + 255) / 256, 256, 0, stream>>>(rec, elist, base, counts, ta);

    k_fw1<<<(N_USER + 63) / 64, 256, 0, stream>>>(d_in[0], cw1, flags, fw1);
    k_fuse<<<(N_USER + 3) / 4, 256, 0, stream>>>(fw1, ta, cw2, cm, flags, d_out);
}

// Round 4
// 586.875 us; speedup vs baseline: 1.4951x; 1.1886x over previous
//
#include <hip/hip_runtime.h>
#include <hip/hip_bf16.h>

#define N_NODES 100000
#define N_USER  50000
#define D_IN    100
#define F_OUT   16
#define N_HEAD  3
#define N_TYPES 3
#define N_EDGES 1600000
#define D2      128
#define N_SEG   (N_TYPES * N_USER)        // 150,000 (t, user) segments
#define N_SEG_PAD (147 * 1024)            // 150,528

typedef __hip_bfloat16 bf16;
static __device__ __forceinline__ float b2f(bf16 x) { return __bfloat162float(x); }

// ---------------- workspace layout (float elements) ----------------
#define OFF_CVT   64
#define OFF_CW    (OFF_CVT)
#define OFF_CB    (OFF_CW + 14400)
#define OFF_CAS   (OFF_CB + 144)
#define OFF_CAT   (OFF_CAS + 144)
#define OFF_CW1   (OFF_CAT + 144)
#define OFF_CW2   (OFF_CW1 + 12800)
#define OFF_CM    (OFF_CW2 + 2048)
#define CVT_TOTAL 29808
#define OFF_REC   29888                    // 300,000 records x 32 f32-words (128 B)
#define OFF_CNT   (OFF_REC + 9600000)      // int[150528]
#define OFF_CUR   (OFF_CNT + N_SEG_PAD)    // int[150528]
#define OFF_BASE  (OFF_CUR + N_SEG_PAD)    // int[150528]
#define OFF_BSUM  (OFF_BASE + N_SEG_PAD)   // int[256]
#define OFF_BOFF  (OFF_BSUM + 256)         // int[256]
#define OFF_ELIST (OFF_BOFF + 256)         // int[4,800,000] (worst case)
#define OFF_TA    (OFF_ELIST + 4800000)    // f32[2,400,000]
// end ~17M floats ~ 69 MB

// ---------------------------------------------------------------------------
// Kernel 0: dtype detection. flags[0]=1 f32 floats, flags[1]=1 int64 edges.
// ---------------------------------------------------------------------------
__global__ void k_detect(const unsigned* __restrict__ hraw,
                         const unsigned* __restrict__ eiraw,
                         int* __restrict__ flags) {
    __shared__ int sane, nz;
    if (threadIdx.x == 0) { sane = 0; nz = 0; }
    __syncthreads();
    int cnt = 0; unsigned o = 0;
    for (int i = threadIdx.x; i < 1024; i += 256) {
        unsigned w = hraw[i];
        unsigned e = (w >> 23) & 0xFF;
        if (e >= 64 && e <= 200) cnt++;
        o |= eiraw[2 * i + 1];
    }
    atomicAdd(&sane, cnt);
    atomicOr(&nz, (int)(o != 0));
    __syncthreads();
    if (threadIdx.x == 0) {
        flags[0] = (sane > 512) ? 1 : 0;
        flags[1] = nz ? 0 : 1;
    }
}

// ---------------------------------------------------------------------------
// Kernel 0b: convert small weight tensors -> f32 workspace
// ---------------------------------------------------------------------------
__global__ __launch_bounds__(256) void k_convert_w(
        const void* __restrict__ W, const void* __restrict__ b,
        const void* __restrict__ as_, const void* __restrict__ at_,
        const void* __restrict__ w1, const void* __restrict__ w2,
        const void* __restrict__ m, const int* __restrict__ flags,
        float* __restrict__ cvt) {
    int i = blockIdx.x * 256 + threadIdx.x;
    if (i >= CVT_TOTAL) return;
    const void* src; int off;
    if      (i < 14400)                 { src = W;   off = i; }
    else if (i < 14400+144)             { src = b;   off = i - 14400; }
    else if (i < 14400+288)             { src = as_; off = i - 14544; }
    else if (i < 14400+432)             { src = at_; off = i - 14688; }
    else if (i < 14400+432+12800)       { src = w1;  off = i - 14832; }
    else if (i < 14400+432+12800+2048)  { src = w2;  off = i - 27632; }
    else                                { src = m;   off = i - 29680; }
    cvt[i] = flags[0] ? ((const float*)src)[off] : b2f(((const bf16*)src)[off]);
}

static __device__ __forceinline__ int load_ei(const void* ei, int f64, size_t pos) {
    return f64 ? (int)((const long long*)ei)[pos] : ((const int*)ei)[pos];
}

// ---------------------------------------------------------------------------
// Kernel 1: fused h@W+b -> scores -> exp -> packed record  (+ edge histogram
// hidden behind the GEMM: atomics with unused result = fire-and-forget)
// rec[t*N_NODES+n] (128B): g[48] bf16 = p_k*hprime, p[3] f32 at word 24
// ---------------------------------------------------------------------------
__global__ __launch_bounds__(256) void k_hp_pack(const void* __restrict__ h,
                                                 const float* __restrict__ cW,
                                                 const float* __restrict__ cb,
                                                 const float* __restrict__ cas,
                                                 const float* __restrict__ cat,
                                                 const void* __restrict__ ei,
                                                 const int* __restrict__ flags,
                                                 int* __restrict__ counts,
                                                 float* __restrict__ rec) {
    __shared__ float hs[64][101];
    __shared__ float wsl[4800];
    __shared__ float psh[64][3];
    const int tid = threadIdx.x;
    const int node0 = blockIdx.x * 64;
    const int f32in = flags[0];
    const int f64ei = flags[1];
    // ---- folded histogram (no waitcnt dependency; hides behind GEMM) ----
    {
        int gid = blockIdx.x * 256 + tid;
        int gsize = gridDim.x * 256;
        for (int i = gid; i < N_TYPES * N_EDGES; i += gsize) {
            int t = i / N_EDGES, e = i - t * N_EDGES;
            int trg = load_ei(ei, f64ei, (size_t)(t * 2 + 1) * N_EDGES + e);
            if ((unsigned)trg < N_USER) atomicAdd(&counts[t * N_USER + trg], 1);
        }
    }
    for (int i = tid; i < 64 * D_IN; i += 256) {
        int r = i / D_IN, c = i % D_IN;
        int n = node0 + r;
        float v = 0.f;
        if (n < N_NODES)
            v = f32in ? ((const float*)h)[(size_t)n * D_IN + c]
                      : b2f(((const bf16*)h)[(size_t)n * D_IN + c]);
        hs[r][c] = v;
    }
    const int u  = tid & 63;
    const int og = tid >> 6;
    for (int t = 0; t < N_TYPES; ++t) {
        __syncthreads();
        for (int i = tid; i < D_IN * 48; i += 256)
            wsl[i] = cW[(size_t)t * D_IN * 48 + i];
        __syncthreads();
        float acc[12];
#pragma unroll
        for (int j = 0; j < 12; ++j) acc[j] = 0.f;
        for (int c = 0; c < D_IN; ++c) {
            float hv = hs[u][c];
            const float4* wr = (const float4*)&wsl[c * 48 + og * 12];
#pragma unroll
            for (int q = 0; q < 3; ++q) {
                float4 wv = wr[q];
                acc[q * 4 + 0] += hv * wv.x;
                acc[q * 4 + 1] += hv * wv.y;
                acc[q * 4 + 2] += hv * wv.z;
                acc[q * 4 + 3] += hv * wv.w;
            }
        }
        __syncthreads();
#pragma unroll
        for (int j = 0; j < 12; ++j)
            wsl[u * 48 + og * 12 + j] = acc[j] + cb[t * 48 + og * 12 + j];
        __syncthreads();
        if (tid < 192) {
            int uu = tid & 63, k = tid >> 6;
            float s = 0.f;
#pragma unroll
            for (int f = 0; f < 16; ++f)
                s += wsl[uu * 48 + k * 16 + f] *
                     (cas[t * 48 + k * 16 + f] + cat[t * 48 + k * 16 + f]);
            s = (s > 0.f) ? s : 0.2f * s;
            psh[uu][k] = __expf(s);
        }
        __syncthreads();
        int n = node0 + u;
        if (n < N_NODES) {
            size_t nodei = (size_t)t * N_NODES + n;
            ushort* ru = (ushort*)rec + nodei * 64;
#pragma unroll
            for (int j = 0; j < 12; ++j) {
                int jj = og * 12 + j;
                float g = psh[u][jj >> 4] * wsl[u * 48 + jj];
                bf16 gb = __float2bfloat16(g);
                ru[jj] = *(ushort*)&gb;
            }
            if (og == 0) {
                float* rf = rec + nodei * 32;
                rf[24] = psh[u][0]; rf[25] = psh[u][1]; rf[26] = psh[u][2];
            }
        }
    }
}

// ---------------------------------------------------------------------------
// CSR scan (3 kernels) + fill
// ---------------------------------------------------------------------------
__global__ __launch_bounds__(256) void k_scan1(const int* __restrict__ counts,
                                               int* __restrict__ bsum) {
    __shared__ int sd[256];
    int b = blockIdx.x, t = threadIdx.x;
    int i0 = b * 1024 + t * 4;
    int s = counts[i0] + counts[i0+1] + counts[i0+2] + counts[i0+3];
    sd[t] = s;
    for (int off = 128; off > 0; off >>= 1) {
        __syncthreads();
        if (t < off) sd[t] += sd[t + off];
    }
    if (t == 0) bsum[b] = sd[0];
}

__global__ void k_scan2(const int* __restrict__ bsum, int* __restrict__ boff) {
    __shared__ int sd[256];
    int t = threadIdx.x;
    int v = (t < 147) ? bsum[t] : 0;
    sd[t] = v;
    for (int off = 1; off < 256; off <<= 1) {
        __syncthreads();
        int x = (t >= off) ? sd[t - off] : 0;
        __syncthreads();
        sd[t] += x;
    }
    __syncthreads();
    if (t < 147) boff[t] = sd[t] - v;
}

__global__ __launch_bounds__(256) void k_scan3(const int* __restrict__ counts,
                                               const int* __restrict__ boff,
                                               int* __restrict__ base) {
    __shared__ int sd[256];
    int b = blockIdx.x, t = threadIdx.x;
    int i0 = b * 1024 + t * 4;
    int c0 = counts[i0], c1 = counts[i0+1], c2 = counts[i0+2], c3 = counts[i0+3];
    int s = c0 + c1 + c2 + c3;
    sd[t] = s;
    for (int off = 1; off < 256; off <<= 1) {
        __syncthreads();
        int x = (t >= off) ? sd[t - off] : 0;
        __syncthreads();
        sd[t] += x;
    }
    __syncthreads();
    int excl = sd[t] - s + boff[b];
    base[i0]   = excl;
    base[i0+1] = excl + c0;
    base[i0+2] = excl + c0 + c1;
    base[i0+3] = excl + c0 + c1 + c2;
}

__global__ __launch_bounds__(256) void k_fill(const void* __restrict__ ei,
                                              const int* __restrict__ flags,
                                              const int* __restrict__ base,
                                              int* __restrict__ cursor,
                                              int* __restrict__ elist) {
    int i = blockIdx.x * 256 + threadIdx.x;
    if (i >= N_TYPES * N_EDGES) return;
    int t = i / N_EDGES, e = i - t * N_EDGES;
    int f64 = flags[1];
    int trg = load_ei(ei, f64, (size_t)(t * 2 + 1) * N_EDGES + e);
    if ((unsigned)trg >= N_USER) return;
    int src = load_ei(ei, f64, (size_t)(t * 2) * N_EDGES + e);
    int tv = t * N_USER + trg;
    int pos = atomicAdd(&cursor[tv], 1);
    elist[base[tv] + pos] = src;
}

// ---------------------------------------------------------------------------
// Kernel 3: gather, unroll-8 per half-wave for MLP. One wave per (t,v).
// virtual edge 0 = self loop. Writes ta[v][t][16] directly.
// ---------------------------------------------------------------------------
__global__ __launch_bounds__(256) void k_gather(const float* __restrict__ rec,
                                                const int* __restrict__ elist,
                                                const int* __restrict__ base,
                                                const int* __restrict__ counts,
                                                float* __restrict__ ta) {
    int wid = (blockIdx.x * 256 + threadIdx.x) >> 6;
    if (wid >= N_SEG) return;
    int lane = threadIdx.x & 63;
    int t = wid / N_USER, v = wid - t * N_USER;
    int cnt = counts[wid] + 1;          // + self loop
    int b0 = base[wid];
    int h = lane >> 5, l = lane & 31;
    const unsigned* recu = (const unsigned*)rec;
    const bool isg = (l < 24);
    const bool isp = (l >= 24) && (l < 27);
    float a0 = 0.f, a1 = 0.f, pacc = 0.f;
    for (int eb = h; eb < cnt; eb += 16) {
        unsigned w[8];
        int val[8];
#pragma unroll
        for (int q = 0; q < 8; ++q) {
            int ee = eb + 2 * q;
            int vq = (ee < cnt);
            int use_list = vq && (ee > 0);
            int idx = b0 + (use_list ? ee - 1 : 0);     // clamped, always in-buffer
            int srcl = elist[idx];                       // unconditional (ILP)
            int src = use_list ? srcl : v;
            val[q] = vq;
            unsigned off = ((unsigned)(t * N_NODES + src) << 5) + l;
            w[q] = recu[off];                            // unconditional (ILP)
        }
#pragma unroll
        for (int q = 0; q < 8; ++q) {
            if (val[q]) {
                a0   += isg ? __uint_as_float(w[q] << 16)        : 0.f;
                a1   += isg ? __uint_as_float(w[q] & 0xffff0000u): 0.f;
                pacc += isp ? __uint_as_float(w[q])              : 0.f;
            }
        }
    }
    a0 += __shfl_xor(a0, 32);
    a1 += __shfl_xor(a1, 32);
    pacc += __shfl_xor(pacc, 32);
    int k = (l >> 3); if (k > 2) k = 2;
    float dk = __shfl(pacc, 24 + k) + 1e-10f;
    float r0 = a0 / dk, r1 = a1 / dk;
    float s0 = r0 + __shfl(r0, (l & 7) + 8) + __shfl(r0, (l & 7) + 16);
    float s1 = r1 + __shfl(r1, (l & 7) + 8) + __shfl(r1, (l & 7) + 16);
    if (lane < 8) {
        float2 o;
        o.x = s0 * (1.f / 3.f);
        o.y = s1 * (1.f / 3.f);
        *(float2*)&ta[(size_t)v * 48 + t * 16 + 2 * lane] = o;
    }
}

// ---------------------------------------------------------------------------
// Kernel 4: fused fw1 GEMM + tanh/softmax/beta-blend + output write.
// block=256, 64 users/block. fw1 kept in registers across both phases.
// ---------------------------------------------------------------------------
__global__ __launch_bounds__(256) void k_fw1_fuse(const void* __restrict__ h,
                                                  const float* __restrict__ cw1,
                                                  const float* __restrict__ cw2,
                                                  const float* __restrict__ cm,
                                                  const float* __restrict__ ta,
                                                  const int* __restrict__ flags,
                                                  void* __restrict__ out) {
    __shared__ float hs[64][101];     // 25.9 KB
    __shared__ float wsl[D_IN][64];   // 25.6 KB
    __shared__ float w2s[F_OUT * D2]; // 8 KB
    __shared__ float ms[D2];
    __shared__ float tas[64][49];     // 12.5 KB (pad 49)
    __shared__ float psum[64][12];    // [u][og*3+t]
    __shared__ float fus[64][16];
    const int tid = threadIdx.x;
    const int v0 = blockIdx.x * 64;
    const int f32in = flags[0];
    for (int i = tid; i < 64 * D_IN; i += 256) {
        int r = i / D_IN, c = i % D_IN;
        int v = v0 + r;
        float x = 0.f;
        if (v < N_USER)
            x = f32in ? ((const float*)h)[(size_t)v * D_IN + c]
                      : b2f(((const bf16*)h)[(size_t)v * D_IN + c]);
        hs[r][c] = x;
    }
    for (int i = tid; i < F_OUT * D2; i += 256) w2s[i] = cw2[i];
    if (tid < D2) ms[tid] = cm[tid];
    {
        int r = tid >> 2, c4 = (tid & 3) * 12;   // 64 users x 48 vals via 256 threads
        int v = v0 + r;
        for (int j = 0; j < 12; ++j)
            tas[r][c4 + j] = (v < N_USER) ? ta[(size_t)v * 48 + c4 + j] : 0.f;
    }
    const int u  = tid & 63;
    const int og = tid >> 6;
    float acc[2][16];
    for (int ph = 0; ph < 2; ++ph) {
        __syncthreads();
        for (int i = tid; i < D_IN * 64; i += 256)
            wsl[i / 64][i % 64] = cw1[(size_t)(i / 64) * D2 + ph * 64 + (i % 64)];
        __syncthreads();
#pragma unroll
        for (int j = 0; j < 16; ++j) acc[ph][j] = 0.f;
        for (int c = 0; c < D_IN; ++c) {
            float hv = hs[u][c];
            const float4* wr = (const float4*)&wsl[c][og * 16];
#pragma unroll
            for (int q = 0; q < 4; ++q) {
                float4 wv = wr[q];
                acc[ph][q * 4 + 0] += hv * wv.x;
                acc[ph][q * 4 + 1] += hv * wv.y;
                acc[ph][q * 4 + 2] += hv * wv.z;
                acc[ph][q * 4 + 3] += hv * wv.w;
            }
        }
    }
    // fusion math: this thread owns cols {ph*64 + og*16 + j}
    float part[3] = {0.f, 0.f, 0.f};
#pragma unroll
    for (int ph = 0; ph < 2; ++ph) {
#pragma unroll
        for (int j = 0; j < 16; ++j) {
            int c = ph * 64 + og * 16 + j;
            float fv = acc[ph][j];
            float mv = ms[c];
#pragma unroll
            for (int t = 0; t < 3; ++t) {
                float z = fv;
#pragma unroll
                for (int f = 0; f < 16; ++f)
                    z += tas[u][t * 16 + f] * w2s[f * D2 + c];
                float q = 1.f - 2.f / (__expf(2.f * z) + 1.f);   // tanh
                part[t] += q * mv;
            }
        }
    }
    psum[u][og * 3 + 0] = part[0];
    psum[u][og * 3 + 1] = part[1];
    psum[u][og * 3 + 2] = part[2];
    __syncthreads();
    if (tid < 64) {
        float sc[3];
#pragma unroll
        for (int t = 0; t < 3; ++t)
            sc[t] = psum[tid][t] + psum[tid][3 + t] + psum[tid][6 + t] + psum[tid][9 + t];
        float mx = fmaxf(sc[0], fmaxf(sc[1], sc[2]));
        float e0 = __expf(sc[0] - mx), e1 = __expf(sc[1] - mx), e2 = __expf(sc[2] - mx);
        float inv = 1.f / (e0 + e1 + e2);
#pragma unroll
        for (int f = 0; f < 16; ++f)
            fus[tid][f] = (e0 * tas[tid][f] + e1 * tas[tid][16 + f] + e2 * tas[tid][32 + f]) * inv;
    }
    __syncthreads();
    // cooperative output write: 64 users x 64 cols
    for (int kq = 0; kq < 16; ++kq) {
        int lin = kq * 256 + tid;
        int r = lin >> 6, c = lin & 63;
        int v = v0 + r;
        if (v < N_USER) {
            float val = (c < 16) ? fus[r][c] : tas[r][c - 16];
            size_t oidx = (size_t)v * 64 + c;
            if (f32in) ((float*)out)[oidx] = val;
            else       ((bf16*)out)[oidx]  = __float2bfloat16(val);
        }
    }
}

// ---------------------------------------------------------------------------
extern "C" void kernel_launch(void* const* d_in, const int* in_sizes, int n_in,
                              void* d_out, int out_size, void* d_ws, size_t ws_size,
                              hipStream_t stream) {
    float* ws = (float*)d_ws;
    int*   flags = (int*)ws;
    float* cvt   = ws + OFF_CVT;
    float* cW    = ws + OFF_CW;
    float* cb    = ws + OFF_CB;
    float* cas   = ws + OFF_CAS;
    float* cat   = ws + OFF_CAT;
    float* cw1   = ws + OFF_CW1;
    float* cw2   = ws + OFF_CW2;
    float* cm    = ws + OFF_CM;
    float* rec   = ws + OFF_REC;
    int*   counts= (int*)(ws + OFF_CNT);
    int*   cursor= (int*)(ws + OFF_CUR);
    int*   base  = (int*)(ws + OFF_BASE);
    int*   bsum  = (int*)(ws + OFF_BSUM);
    int*   boff  = (int*)(ws + OFF_BOFF);
    int*   elist = (int*)(ws + OFF_ELIST);
    float* ta    = ws + OFF_TA;

    k_detect<<<1, 256, 0, stream>>>((const unsigned*)d_in[0], (const unsigned*)d_in[8], flags);
    k_convert_w<<<(CVT_TOTAL + 255) / 256, 256, 0, stream>>>(
        d_in[1], d_in[2], d_in[3], d_in[4], d_in[5], d_in[6], d_in[7], flags, cvt);
    hipMemsetAsync(counts, 0, (size_t)2 * N_SEG_PAD * sizeof(int), stream);

    k_hp_pack<<<(N_NODES + 63) / 64, 256, 0, stream>>>(
        d_in[0], cW, cb, cas, cat, d_in[8], flags, counts, rec);

    k_scan1<<<147, 256, 0, stream>>>(counts, bsum);
    k_scan2<<<1, 256, 0, stream>>>(bsum, boff);
    k_scan3<<<147, 256, 0, stream>>>(counts, boff, base);
    int eb = (N_TYPES * N_EDGES + 255) / 256;
    k_fill<<<eb, 256, 0, stream>>>(d_in[8], flags, base, cursor, elist);

    k_gather<<<(N_SEG * 64 + 255) / 256, 256, 0, stream>>>(rec, elist, base, counts, ta);

    k_fw1_fuse<<<(N_USER + 63) / 64, 256, 0, stream>>>(
        d_in[0], cw1, cw2, cm, ta, flags, d_out);
}